// Round 5
// baseline (38.389 us; speedup 1.0000x reference)
//
#include <hip/hip_runtime.h>

#define W_LEN 4
#define OUT_C 3
#define KK    3
#define HH    16
#define FC_HID 6
#define W_NEW 2          // W_LEN - K + 1
#define FC_IN 96         // OUT_C * W_NEW * HH
#define TT    16384
#define BB    32

__device__ __forceinline__ float tanh_fast(float x) {
    // tanh(x) = 1 - 2/(2^(x*2*log2e)+1): mul, exp2, add, rcp, fma
    float e = __builtin_amdgcn_exp2f(x * 2.8853900817779268f);
    float r = __builtin_amdgcn_rcpf(e + 1.0f);
    return fmaf(-2.0f, r, 1.0f);
}

// Two consecutive positions per thread; 3 conv rows per pair (row reuse).
// This round: the oc-loop is ROLLED (unroll(disable)) to cut code size ~3x
// (fully-unrolled body was ~25-30KB, thrashing the 32KB I$). All weight
// addresses remain wave-uniform (arg + SGPR-computed offset -> s_load);
// all register arrays (rows, h_a/h_b) keep compile-time indices (c, j, kc
// unrolled) so nothing drops to scratch.
__global__ __launch_bounds__(256, 2)
void rvtdcnn_fused5(
    const float* __restrict__ x,
    const float* __restrict__ conv_w,
    const float* __restrict__ conv_b,
    const float* __restrict__ fc_hid_w,
    const float* __restrict__ fc_hid_b,
    const float* __restrict__ fc_out_w,
    const float* __restrict__ fc_out_b,
    float* __restrict__ out)
{
    const int gid = blockIdx.x * blockDim.x + threadIdx.x;   // [0, B*T/2)
    const int b  = gid >> 13;            // / (TT/2)
    const int t0 = (gid & 8191) << 1;    // even position

    const float4* x4 = reinterpret_cast<const float4*>(x) + (size_t)(b * TT + t0) * (HH / 4);

#define LOAD_ROW(R, OFF)                                                     \
    do {                                                                     \
        if (t0 + (OFF) < 0) {                                                \
            _Pragma("unroll") for (int c = 0; c < HH; ++c) R[c] = 0.0f;      \
        } else {                                                             \
            _Pragma("unroll") for (int q = 0; q < HH / 4; ++q) {             \
                float4 v = x4[(OFF) * (HH / 4) + q];                         \
                R[q * 4 + 0] = v.x; R[q * 4 + 1] = v.y;                      \
                R[q * 4 + 2] = v.z; R[q * 4 + 3] = v.w;                      \
            }                                                                \
        }                                                                    \
    } while (0)

    float h_a[FC_HID], h_b[FC_HID];
    #pragma unroll
    for (int j = 0; j < FC_HID; ++j) {
        const float bj = fc_hid_b[j];
        h_a[j] = bj;
        h_b[j] = bj;
    }

    // Rolled-oc conv row. Per oc: 9 conv weights + bias fetched at a
    // wave-uniform runtime address (s_load, scalar L1 hot), 16 features
    // computed (c unrolled), each scattered into h_a/h_b (j unrolled,
    // fc_hid_w at uniform runtime address -> s_load).
#define CONV_ROW(RA, RB, RC, DO_A, IA, DO_B, IB)                             \
    _Pragma("clang loop unroll(disable)")                                    \
    for (int oc = 0; oc < OUT_C; ++oc) {                                     \
        const float* cwp = conv_w + oc * (KK * KK);                          \
        const float w00 = cwp[0], w01 = cwp[1], w02 = cwp[2];                \
        const float w10 = cwp[3], w11 = cwp[4], w12 = cwp[5];                \
        const float w20 = cwp[6], w21 = cwp[7], w22 = cwp[8];                \
        const float bias = conv_b[oc];                                       \
        const float* fwA = fc_hid_w + (oc * W_NEW + (IA)) * HH;              \
        const float* fwB = fc_hid_w + (oc * W_NEW + (IB)) * HH;              \
        _Pragma("unroll") for (int c = 0; c < HH; ++c) {                     \
            float acc = bias;                                                \
            if (c > 0) {                                                     \
                acc = fmaf(RA[c - 1], w00, acc);                             \
                acc = fmaf(RB[c - 1], w10, acc);                             \
                acc = fmaf(RC[c - 1], w20, acc);                             \
            }                                                                \
            acc = fmaf(RA[c], w01, acc);                                     \
            acc = fmaf(RB[c], w11, acc);                                     \
            acc = fmaf(RC[c], w21, acc);                                     \
            if (c < HH - 1) {                                                \
                acc = fmaf(RA[c + 1], w02, acc);                             \
                acc = fmaf(RB[c + 1], w12, acc);                             \
                acc = fmaf(RC[c + 1], w22, acc);                             \
            }                                                                \
            const float f = tanh_fast(acc);                                  \
            if (DO_A) {                                                      \
                _Pragma("unroll") for (int j = 0; j < FC_HID; ++j)           \
                    h_a[j] = fmaf(f, fwA[j * FC_IN + c], h_a[j]);            \
            }                                                                \
            if (DO_B) {                                                      \
                _Pragma("unroll") for (int j = 0; j < FC_HID; ++j)           \
                    h_b[j] = fmaf(f, fwB[j * FC_IN + c], h_b[j]);            \
            }                                                                \
        }                                                                    \
    }

    float rA[HH], rB[HH], rC[HH], rD[HH];
    LOAD_ROW(rA, -3);
    LOAD_ROW(rB, -2);
    LOAD_ROW(rC, -1);
    LOAD_ROW(rD,  0);

    // crow0: rows (t0-3..t0-1) -> pos t0 wr=0; rA (t0-3) dies here
    CONV_ROW(rA, rB, rC, true, 0, false, 1);
    LOAD_ROW(rA, 1);                       // slot reuse: rA <- row t0+1
    // crow1: rows (t0-2..t0)   -> pos t0 wr=1, pos t0+1 wr=0
    CONV_ROW(rB, rC, rD, true, 1, true, 0);
    // crow2: rows (t0-1..t0+1) -> pos t0+1 wr=1
    CONV_ROW(rC, rD, rA, false, 0, true, 1);

    // ---- FC1 tanh -> FC2 for both positions ----
    float ya0 = fc_out_b[0], ya1 = fc_out_b[1];
    float yb0 = ya0, yb1 = ya1;
    #pragma unroll
    for (int j = 0; j < FC_HID; ++j) {
        const float w0 = fc_out_w[j];
        const float w1 = fc_out_w[FC_HID + j];
        const float ha = tanh_fast(h_a[j]);
        const float hb = tanh_fast(h_b[j]);
        ya0 = fmaf(ha, w0, ya0);
        ya1 = fmaf(ha, w1, ya1);
        yb0 = fmaf(hb, w0, yb0);
        yb1 = fmaf(hb, w1, yb1);
    }

    float4 o;
    o.x = ya0; o.y = ya1; o.z = yb0; o.w = yb1;
    reinterpret_cast<float4*>(out)[(b * TT + t0) >> 1] = o;

#undef LOAD_ROW
#undef CONV_ROW
}

extern "C" void kernel_launch(void* const* d_in, const int* in_sizes, int n_in,
                              void* d_out, int out_size, void* d_ws, size_t ws_size,
                              hipStream_t stream) {
    const float* x        = (const float*)d_in[0];
    const float* conv_w   = (const float*)d_in[1];
    const float* conv_b   = (const float*)d_in[2];
    const float* fc_hid_w = (const float*)d_in[3];
    const float* fc_hid_b = (const float*)d_in[4];
    const float* fc_out_w = (const float*)d_in[5];
    const float* fc_out_b = (const float*)d_in[6];
    float* out = (float*)d_out;

    const int n_pairs = BB * TT / 2;       // 262144 threads
    const int block = 256;
    const int grid = n_pairs / block;      // 1024 blocks = 4 blocks/CU, uniform
    rvtdcnn_fused5<<<grid, block, 0, stream>>>(x, conv_w, conv_b, fc_hid_w, fc_hid_b,
                                               fc_out_w, fc_out_b, out);
}